// Round 2
// baseline (13826.317 us; speedup 1.0000x reference)
//
#include <hip/hip_runtime.h>

#define NA 100000
#define NP 1600000
#define DA 75
#define DP 14
#define H  50
#define PPB 64

// ---------------------------------------------------------------------------
// K1: Xt[a][c] = af[a] @ W_AP[0:75,c] + b_AP[c] ; Xb[a][c] = af[a] @ W_AP[75:150,c]
// lane c owns output column c; weight columns live in registers (150 VGPR).
// ---------------------------------------------------------------------------
__global__ __launch_bounds__(256) void k_atom_ap(
    const float* __restrict__ af, const float* __restrict__ W_AP,
    const float* __restrict__ b_AP, float* __restrict__ Xt,
    float* __restrict__ Xb, int nWaves) {
  const int c = threadIdx.x & 63;
  const int wave = (blockIdx.x * 256 + threadIdx.x) >> 6;
  const bool act = c < H;
  float wt[DA], wb[DA];
  float bias = 0.f;
  if (act) {
    bias = b_AP[c];
#pragma unroll
    for (int k = 0; k < DA; ++k) {
      wt[k] = W_AP[k * H + c];
      wb[k] = W_AP[(DA + k) * H + c];
    }
  }
  for (int a = wave; a < NA; a += nWaves) {
    const float* __restrict__ row = af + (size_t)a * DA;
    float xt = bias, xb = 0.f;
#pragma unroll
    for (int k = 0; k < DA; ++k) {
      const float f = row[k];  // wave-uniform address -> broadcast
      xt = fmaf(f, wt[k], xt);
      xb = fmaf(f, wb[k], xb);
    }
    if (act) {
      Xt[(size_t)a * H + c] = xt;
      Xb[(size_t)a * H + c] = xb;
    }
  }
}

// ---------------------------------------------------------------------------
// K2: atom branch. Per wave-iteration one atom:
//   AA = relu(af@W_AA+b), PA = segment-sum of relu(pf@W_PA+b) over this
//   atom's pair range (binary search in sorted pair_split), then
//   A = relu([AA,PA]@W_A + b_A). Cross-lane dot via per-wave LDS bounce.
// Weight columns in registers: 75+14+100 = 189 VGPR -> ~2 waves/SIMD.
// ---------------------------------------------------------------------------
__global__ __launch_bounds__(256) void k_atom_out(
    const float* __restrict__ af, const float* __restrict__ pf,
    const int* __restrict__ split,
    const float* __restrict__ W_AA, const float* __restrict__ b_AA,
    const float* __restrict__ W_PA, const float* __restrict__ b_PA,
    const float* __restrict__ W_A, const float* __restrict__ b_A,
    float* __restrict__ A_out, int nWaves) {
  __shared__ __align__(16) float buf[4][104];
  const int w = threadIdx.x >> 6;
  const int c = threadIdx.x & 63;
  const bool act = c < H;
  float waa[DA], wpa[DP], wa[2 * H];
  float baa = 0.f, bpa = 0.f, ba = 0.f;
  if (act) {
    baa = b_AA[c]; bpa = b_PA[c]; ba = b_A[c];
#pragma unroll
    for (int k = 0; k < DA; ++k) waa[k] = W_AA[k * H + c];
#pragma unroll
    for (int k = 0; k < DP; ++k) wpa[k] = W_PA[k * H + c];
#pragma unroll
    for (int k = 0; k < 2 * H; ++k) wa[k] = W_A[k * H + c];
  }
  const int wave0 = blockIdx.x * 4 + w;
  for (int a = wave0; a < NA; a += nWaves) {
    const float* __restrict__ row = af + (size_t)a * DA;
    float aa = baa;
#pragma unroll
    for (int k = 0; k < DA; ++k) aa = fmaf(row[k], waa[k], aa);
    aa = fmaxf(aa, 0.f);
    // pair range [s,e) for atom a (pair_split sorted ascending)
    int lo = 0, hi = NP;
    while (lo < hi) { int m = (lo + hi) >> 1; if (split[m] < a) lo = m + 1; else hi = m; }
    const int s = lo;
    hi = NP;
    while (lo < hi) { int m = (lo + hi) >> 1; if (split[m] <= a) lo = m + 1; else hi = m; }
    const int e = lo;
    float pa = 0.f;
    for (int p = s; p < e; ++p) {
      const float* __restrict__ pr = pf + (size_t)p * DP;
      float v = bpa;
#pragma unroll
      for (int k = 0; k < DP; ++k) v = fmaf(pr[k], wpa[k], v);
      pa += fmaxf(v, 0.f);
    }
    if (act) { buf[w][c] = aa; buf[w][H + c] = pa; }
    __builtin_amdgcn_wave_barrier();  // in-wave LDS ops are in-order; fence compiler
    float acc2 = ba;
    const float4* __restrict__ b4 = (const float4*)(&buf[w][0]);
#pragma unroll
    for (int k4 = 0; k4 < 25; ++k4) {
      const float4 v = b4[k4];
      acc2 = fmaf(v.x, wa[4 * k4 + 0], acc2);
      acc2 = fmaf(v.y, wa[4 * k4 + 1], acc2);
      acc2 = fmaf(v.z, wa[4 * k4 + 2], acc2);
      acc2 = fmaf(v.w, wa[4 * k4 + 3], acc2);
    }
    __builtin_amdgcn_wave_barrier();
    if (act) A_out[(size_t)a * H + c] = fmaxf(acc2, 0.f);
  }
}

// ---------------------------------------------------------------------------
// K3: pair branch, 64 pairs per block.
// Phase 1 (lane c = output col): S = relu(Xt[i]+Xb[j]) + relu(Xt[j]+Xb[i]),
//   PP = relu(pf@W_PP+b) -> LDS SP[64][100] (stride 108: 2-way conflicts only).
// Phase 2: C[64x50] = SP[64x100] @ W_P[100x50(pad 64)], 4x4 register tile
//   per thread, float4 LDS reads, relu + float2 stores.
// ---------------------------------------------------------------------------
__global__ __launch_bounds__(256) void k_pair_out(
    const float* __restrict__ pf, const int* __restrict__ a2p,
    const float* __restrict__ Xt, const float* __restrict__ Xb,
    const float* __restrict__ W_PP, const float* __restrict__ b_PP,
    const float* __restrict__ W_P, const float* __restrict__ b_P,
    float* __restrict__ P_out) {
  __shared__ __align__(16) float SP[PPB][108];
  __shared__ __align__(16) float WPl[2 * H][64];
  __shared__ int IJ[PPB][2];
  const int t = threadIdx.x;
  const int pBase = blockIdx.x * PPB;
  // stage W_P (zero-pad cols >= H)
  for (int idx = t; idx < 2 * H * 64; idx += 256) {
    const int k = idx >> 6, cc = idx & 63;
    WPl[k][cc] = (cc < H) ? W_P[k * H + cc] : 0.f;
  }
  // stage atom_to_pair for this block
  if (t < 2 * PPB) ((int*)IJ)[t] = a2p[2 * pBase + t];
  __syncthreads();

  const int w = t >> 6, c = t & 63;
  const bool act = c < H;
  float wpp[DP];
  float bpp = 0.f;
  if (act) {
    bpp = b_PP[c];
#pragma unroll
    for (int k = 0; k < DP; ++k) wpp[k] = W_PP[k * H + c];
  }
  // phase 1: wave w handles pairs q*4+w
#pragma unroll 4
  for (int q = 0; q < 16; ++q) {
    const int pl = q * 4 + w;
    const int p = pBase + pl;
    const int i = IJ[pl][0], j = IJ[pl][1];
    if (act) {
      const float xti = Xt[(size_t)i * H + c];
      const float xbj = Xb[(size_t)j * H + c];
      const float xtj = Xt[(size_t)j * H + c];
      const float xbi = Xb[(size_t)i * H + c];
      const float s = fmaxf(xti + xbj, 0.f) + fmaxf(xtj + xbi, 0.f);
      const float* __restrict__ pr = pf + (size_t)p * DP;
      float v = bpp;
#pragma unroll
      for (int k = 0; k < DP; ++k) v = fmaf(pr[k], wpp[k], v);
      SP[pl][c] = s;
      SP[pl][H + c] = fmaxf(v, 0.f);
    }
  }
  __syncthreads();

  // phase 2
  const int tx = t & 15, ty = t >> 4;
  float acc[4][4];
#pragma unroll
  for (int qq = 0; qq < 4; ++qq) {
    const int col = 4 * tx + qq;
    const float b = (col < H) ? b_P[col] : 0.f;
#pragma unroll
    for (int r = 0; r < 4; ++r) acc[r][qq] = b;
  }
#pragma unroll
  for (int k4 = 0; k4 < 25; ++k4) {
    float4 av[4];
#pragma unroll
    for (int r = 0; r < 4; ++r) av[r] = *(const float4*)(&SP[4 * ty + r][4 * k4]);
#pragma unroll
    for (int kk = 0; kk < 4; ++kk) {
      const float4 bv = *(const float4*)(&WPl[4 * k4 + kk][4 * tx]);
#pragma unroll
      for (int r = 0; r < 4; ++r) {
        const float a = (&av[r].x)[kk];
        acc[r][0] = fmaf(a, bv.x, acc[r][0]);
        acc[r][1] = fmaf(a, bv.y, acc[r][1]);
        acc[r][2] = fmaf(a, bv.z, acc[r][2]);
        acc[r][3] = fmaf(a, bv.w, acc[r][3]);
      }
    }
  }
  // store (rows are 200B: use float2, 8B-aligned for all p)
  const int col0 = 4 * tx;
  if (col0 < H) {
#pragma unroll
    for (int r = 0; r < 4; ++r) {
      const size_t base = (size_t)(pBase + 4 * ty + r) * H;
      float2 v0 = make_float2(fmaxf(acc[r][0], 0.f), fmaxf(acc[r][1], 0.f));
      *(float2*)(&P_out[base + col0]) = v0;
      if (col0 + 2 < H) {
        float2 v1 = make_float2(fmaxf(acc[r][2], 0.f), fmaxf(acc[r][3], 0.f));
        *(float2*)(&P_out[base + col0 + 2]) = v1;
      }
    }
  }
}

extern "C" void kernel_launch(void* const* d_in, const int* in_sizes, int n_in,
                              void* d_out, int out_size, void* d_ws, size_t ws_size,
                              hipStream_t stream) {
  const float* af   = (const float*)d_in[0];
  const float* pf   = (const float*)d_in[1];
  const int*   split= (const int*)d_in[2];
  const int*   a2p  = (const int*)d_in[3];
  const float* W_AA = (const float*)d_in[4];
  const float* b_AA = (const float*)d_in[5];
  const float* W_PA = (const float*)d_in[6];
  const float* b_PA = (const float*)d_in[7];
  const float* W_A  = (const float*)d_in[8];
  const float* b_A  = (const float*)d_in[9];
  const float* W_AP = (const float*)d_in[10];
  const float* b_AP = (const float*)d_in[11];
  const float* W_PP = (const float*)d_in[12];
  const float* b_PP = (const float*)d_in[13];
  const float* W_P  = (const float*)d_in[14];
  const float* b_P  = (const float*)d_in[15];

  float* A_out = (float*)d_out;
  float* P_out = A_out + (size_t)NA * H;
  float* Xt = (float*)d_ws;
  float* Xb = Xt + (size_t)NA * H;

  k_atom_ap<<<1024, 256, 0, stream>>>(af, W_AP, b_AP, Xt, Xb, 1024 * 4);
  k_atom_out<<<1024, 256, 0, stream>>>(af, pf, split, W_AA, b_AA, W_PA, b_PA,
                                       W_A, b_A, A_out, 1024 * 4);
  k_pair_out<<<NP / PPB, 256, 0, stream>>>(pf, a2p, Xt, Xb, W_PP, b_PP, W_P, b_P,
                                           P_out);
}

// Round 3
// 2393.960 us; speedup vs baseline: 5.7755x; 5.7755x over previous
//
#include <hip/hip_runtime.h>
#include <hip/hip_bf16.h>

#define NA 100000
#define NP 1600000
#define DA 75
#define DP 14
#define H  50
#define ASTR 136  // bf16 elems per LDS A row / WT row: 128 (padded K) + 8 pad

typedef short short8 __attribute__((ext_vector_type(8)));
typedef float f32x4 __attribute__((ext_vector_type(4)));

static __device__ __forceinline__ short f2bf(float x) {
  __hip_bfloat16 b = __float2bfloat16(x);
  return *reinterpret_cast<short*>(&b);
}

// ---------------------------------------------------------------------------
// K0: WT[n][k] = bf16(W_P[k][n]), zero-padded to [64][136] (K pad 100->128).
// ---------------------------------------------------------------------------
__global__ __launch_bounds__(256) void k_prep_wt(const float* __restrict__ W_P,
                                                 short* __restrict__ WT) {
  const int idx = blockIdx.x * 256 + threadIdx.x;
  if (idx < 64 * ASTR) {
    const int n = idx / ASTR, k = idx % ASTR;
    const float v = (n < H && k < 2 * H) ? W_P[k * H + n] : 0.f;
    WT[idx] = f2bf(v);
  }
}

// ---------------------------------------------------------------------------
// K1: Xt = af @ W_AP[:75] + b_AP ; Xb = af @ W_AP[75:]  (f32, lane=col)
// ---------------------------------------------------------------------------
__global__ __launch_bounds__(256) void k_atom_ap(
    const float* __restrict__ af, const float* __restrict__ W_AP,
    const float* __restrict__ b_AP, float* __restrict__ Xt,
    float* __restrict__ Xb, int nWaves) {
  const int c = threadIdx.x & 63;
  const int wave = (blockIdx.x * 256 + threadIdx.x) >> 6;
  const bool act = c < H;
  float wt[DA], wb[DA];
  float bias = 0.f;
  if (act) {
    bias = b_AP[c];
#pragma unroll
    for (int k = 0; k < DA; ++k) {
      wt[k] = W_AP[k * H + c];
      wb[k] = W_AP[(DA + k) * H + c];
    }
  }
  for (int a = wave; a < NA; a += nWaves) {
    const float* __restrict__ row = af + (size_t)a * DA;
    float xt = bias, xb = 0.f;
#pragma unroll
    for (int k = 0; k < DA; ++k) {
      const float f = row[k];
      xt = fmaf(f, wt[k], xt);
      xb = fmaf(f, wb[k], xb);
    }
    if (act) {
      Xt[(size_t)a * H + c] = xt;
      Xb[(size_t)a * H + c] = xb;
    }
  }
}

// ---------------------------------------------------------------------------
// K2: atom branch. W_A lives in LDS (not 100 VGPRs -> no spill risk).
// ---------------------------------------------------------------------------
__global__ __launch_bounds__(256) void k_atom_out(
    const float* __restrict__ af, const float* __restrict__ pf,
    const int* __restrict__ split,
    const float* __restrict__ W_AA, const float* __restrict__ b_AA,
    const float* __restrict__ W_PA, const float* __restrict__ b_PA,
    const float* __restrict__ W_A, const float* __restrict__ b_A,
    float* __restrict__ A_out, int nWaves) {
  __shared__ float WA[2 * H][64];            // 25.6 KB, zero-padded cols
  __shared__ __align__(16) float buf[4][104];
  const int t = threadIdx.x;
  for (int idx = t; idx < 2 * H * 64; idx += 256) {
    const int k = idx >> 6, cc = idx & 63;
    WA[k][cc] = (cc < H) ? W_A[k * H + cc] : 0.f;
  }
  __syncthreads();
  const int w = t >> 6, c = t & 63;
  const bool act = c < H;
  float waa[DA], wpa[DP];
  float baa = 0.f, bpa = 0.f, ba = 0.f;
  if (act) {
    baa = b_AA[c]; bpa = b_PA[c]; ba = b_A[c];
#pragma unroll
    for (int k = 0; k < DA; ++k) waa[k] = W_AA[k * H + c];
#pragma unroll
    for (int k = 0; k < DP; ++k) wpa[k] = W_PA[k * H + c];
  }
  const int wave0 = blockIdx.x * 4 + w;
  for (int a = wave0; a < NA; a += nWaves) {
    const float* __restrict__ row = af + (size_t)a * DA;
    float aa = baa;
#pragma unroll
    for (int k = 0; k < DA; ++k) aa = fmaf(row[k], waa[k], aa);
    aa = fmaxf(aa, 0.f);
    int lo = 0, hi = NP;
    while (lo < hi) { int m = (lo + hi) >> 1; if (split[m] < a) lo = m + 1; else hi = m; }
    const int s = lo;
    hi = NP;
    while (lo < hi) { int m = (lo + hi) >> 1; if (split[m] <= a) lo = m + 1; else hi = m; }
    const int e = lo;
    float pa = 0.f;
    for (int p = s; p < e; ++p) {
      const float2* __restrict__ pr = (const float2*)(pf + (size_t)p * DP);
      float v = bpa;
#pragma unroll
      for (int k = 0; k < 7; ++k) {
        const float2 f = pr[k];
        v = fmaf(f.x, wpa[2 * k], v);
        v = fmaf(f.y, wpa[2 * k + 1], v);
      }
      pa += fmaxf(v, 0.f);
    }
    if (act) { buf[w][c] = aa; buf[w][H + c] = pa; }
    __builtin_amdgcn_wave_barrier();
    float acc2 = ba;
    const float4* __restrict__ b4 = (const float4*)(&buf[w][0]);
#pragma unroll
    for (int k4 = 0; k4 < 25; ++k4) {
      const float4 vv = b4[k4];
      acc2 = fmaf(vv.x, WA[4 * k4 + 0][c], acc2);
      acc2 = fmaf(vv.y, WA[4 * k4 + 1][c], acc2);
      acc2 = fmaf(vv.z, WA[4 * k4 + 2][c], acc2);
      acc2 = fmaf(vv.w, WA[4 * k4 + 3][c], acc2);
    }
    __builtin_amdgcn_wave_barrier();
    if (act) A_out[(size_t)a * H + c] = fmaxf(acc2, 0.f);
  }
}

// ---------------------------------------------------------------------------
// K3: pair branch. Wave-independent 16-pair strips; phase 2 via bf16 MFMA.
//   A (LDS, bf16): [16 pairs][136] = S(0..49) | PP(50..99) | zeros(100..127)
//   B (global, bf16): WT[64 n][136 k]  (W_P^T, padded) -> register frags
//   D = A@B^T-ish: P[p][n] = sum_k A[p][k] * WT[n][k]
// mfma_f32_16x16x32_bf16 layouts (per guide §3):
//   A-frag: lane l -> row l&15,  k = (l>>4)*8 + e   (ds_read_b128)
//   B-frag: lane l -> col l&15,  k = (l>>4)*8 + e   (global dwordx4, L2-hot)
//   C/D:    lane l -> col l&15,  row = (l>>4)*4 + r
// ---------------------------------------------------------------------------
__global__ __launch_bounds__(256) void k_pair_out(
    const float* __restrict__ pf, const int* __restrict__ a2p,
    const float* __restrict__ Xt, const float* __restrict__ Xb,
    const float* __restrict__ W_PP, const float* __restrict__ b_PP,
    const short* __restrict__ WT, const float* __restrict__ b_P,
    float* __restrict__ P_out) {
  __shared__ __align__(16) short A[4][16 * ASTR];  // 4 x 4352 B
  const int t = threadIdx.x, w = t >> 6, l = t & 63;
  const int pBase = blockIdx.x * 64 + w * 16;
  short* __restrict__ As = &A[w][0];

  // zero this wave's strip (covers K-pad cols 100..127)
  {
    const short8 z = {0, 0, 0, 0, 0, 0, 0, 0};
    for (int idx = l; idx < 16 * ASTR / 8; idx += 64)
      ((short8*)As)[idx] = z;
  }
  __builtin_amdgcn_wave_barrier();

  const bool act = l < H;
  float wpp[DP];
  float bpp = 0.f;
  if (act) {
    bpp = b_PP[l];
#pragma unroll
    for (int k = 0; k < DP; ++k) wpp[k] = W_PP[k * H + l];
  }
  // phase 1: 16 pairs, lane = feature column
#pragma unroll 2
  for (int q = 0; q < 16; ++q) {
    const int p = pBase + q;
    const int i = a2p[2 * p], j = a2p[2 * p + 1];
    if (act) {
      const float s = fmaxf(Xt[(size_t)i * H + l] + Xb[(size_t)j * H + l], 0.f) +
                      fmaxf(Xt[(size_t)j * H + l] + Xb[(size_t)i * H + l], 0.f);
      const float2* __restrict__ pr = (const float2*)(pf + (size_t)p * DP);
      float v = bpp;
#pragma unroll
      for (int k = 0; k < 7; ++k) {
        const float2 f = pr[k];
        v = fmaf(f.x, wpp[2 * k], v);
        v = fmaf(f.y, wpp[2 * k + 1], v);
      }
      As[q * ASTR + l] = f2bf(s);
      As[q * ASTR + H + l] = f2bf(fmaxf(v, 0.f));
    }
  }
  __builtin_amdgcn_wave_barrier();

  // phase 2: 16x64 output strip = 4 col-tiles x 4 K-steps of MFMA
  const int lr = l & 15, lg = l >> 4;
  short8 bfrag[16];
#pragma unroll
  for (int nt = 0; nt < 4; ++nt)
#pragma unroll
    for (int ks = 0; ks < 4; ++ks)
      bfrag[nt * 4 + ks] =
          *(const short8*)(WT + (nt * 16 + lr) * ASTR + ks * 32 + lg * 8);

  f32x4 acc[4];
#pragma unroll
  for (int nt = 0; nt < 4; ++nt) {
    const int col = nt * 16 + lr;
    const float b = (col < H) ? b_P[col] : 0.f;
    acc[nt] = (f32x4){b, b, b, b};
  }
  short8 afr[4];
#pragma unroll
  for (int ks = 0; ks < 4; ++ks)
    afr[ks] = *(const short8*)(As + lr * ASTR + ks * 32 + lg * 8);
#pragma unroll
  for (int nt = 0; nt < 4; ++nt)
#pragma unroll
    for (int ks = 0; ks < 4; ++ks)
      acc[nt] = __builtin_amdgcn_mfma_f32_16x16x32_bf16(afr[ks], bfrag[nt * 4 + ks],
                                                        acc[nt], 0, 0, 0);
  // epilogue: relu + store (cols >= 50 masked)
#pragma unroll
  for (int nt = 0; nt < 4; ++nt) {
    const int col = nt * 16 + lr;
    if (col < H) {
#pragma unroll
      for (int r = 0; r < 4; ++r) {
        const size_t p = (size_t)(pBase + lg * 4 + r);
        P_out[p * H + col] = fmaxf(acc[nt][r], 0.f);
      }
    }
  }
}

extern "C" void kernel_launch(void* const* d_in, const int* in_sizes, int n_in,
                              void* d_out, int out_size, void* d_ws, size_t ws_size,
                              hipStream_t stream) {
  const float* af   = (const float*)d_in[0];
  const float* pf   = (const float*)d_in[1];
  const int*   split= (const int*)d_in[2];
  const int*   a2p  = (const int*)d_in[3];
  const float* W_AA = (const float*)d_in[4];
  const float* b_AA = (const float*)d_in[5];
  const float* W_PA = (const float*)d_in[6];
  const float* b_PA = (const float*)d_in[7];
  const float* W_A  = (const float*)d_in[8];
  const float* b_A  = (const float*)d_in[9];
  const float* W_AP = (const float*)d_in[10];
  const float* b_AP = (const float*)d_in[11];
  const float* W_PP = (const float*)d_in[12];
  const float* b_PP = (const float*)d_in[13];
  const float* W_P  = (const float*)d_in[14];
  const float* b_P  = (const float*)d_in[15];

  float* A_out = (float*)d_out;
  float* P_out = A_out + (size_t)NA * H;
  float* Xt = (float*)d_ws;
  float* Xb = Xt + (size_t)NA * H;
  short* WT = (short*)(Xb + (size_t)NA * H);  // 64*136 bf16 = 17.4 KB

  k_prep_wt<<<(64 * ASTR + 255) / 256, 256, 0, stream>>>(W_P, WT);
  k_atom_ap<<<1024, 256, 0, stream>>>(af, W_AP, b_AP, Xt, Xb, 1024 * 4);
  k_atom_out<<<1024, 256, 0, stream>>>(af, pf, split, W_AA, b_AA, W_PA, b_PA,
                                       W_A, b_A, A_out, 1024 * 4);
  k_pair_out<<<NP / 64, 256, 0, stream>>>(pf, a2p, Xt, Xb, W_PP, b_PP, WT, b_P,
                                          P_out);
}

// Round 4
// 1618.568 us; speedup vs baseline: 8.5423x; 1.4791x over previous
//
#include <hip/hip_runtime.h>
#include <hip/hip_bf16.h>

#define NA 100000
#define NP 1600000
#define DA 75
#define DP 14
#define H  50
#define ASTR 136  // bf16 elems per LDS A row / WT row: 128 (padded K) + 8 pad

typedef short short8 __attribute__((ext_vector_type(8)));
typedef float f32x4 __attribute__((ext_vector_type(4)));

static __device__ __forceinline__ short f2bf(float x) {
  __hip_bfloat16 b = __float2bfloat16(x);
  return *reinterpret_cast<short*>(&b);
}

// ---------------------------------------------------------------------------
// K-1: zero PAacc (d_ws is poisoned 0xAA before every launch).
// ---------------------------------------------------------------------------
__global__ __launch_bounds__(256) void k_zero(float4* __restrict__ p, int n4) {
  const int stride = gridDim.x * 256;
  for (int i = blockIdx.x * 256 + threadIdx.x; i < n4; i += stride)
    p[i] = make_float4(0.f, 0.f, 0.f, 0.f);
}

// ---------------------------------------------------------------------------
// K0: WT[n][k] = bf16(W_P[k][n]), zero-padded to [64][136] (K pad 100->128).
// ---------------------------------------------------------------------------
__global__ __launch_bounds__(256) void k_prep_wt(const float* __restrict__ W_P,
                                                 short* __restrict__ WT) {
  const int idx = blockIdx.x * 256 + threadIdx.x;
  if (idx < 64 * ASTR) {
    const int n = idx / ASTR, k = idx % ASTR;
    const float v = (n < H && k < 2 * H) ? W_P[k * H + n] : 0.f;
    WT[idx] = f2bf(v);
  }
}

// ---------------------------------------------------------------------------
// K1: Xt = af @ W_AP[:75] + b_AP ; Xb = af @ W_AP[75:]  (f32, lane=col)
// ---------------------------------------------------------------------------
__global__ __launch_bounds__(256) void k_atom_ap(
    const float* __restrict__ af, const float* __restrict__ W_AP,
    const float* __restrict__ b_AP, float* __restrict__ Xt,
    float* __restrict__ Xb, int nWaves) {
  const int c = threadIdx.x & 63;
  const int wave = (blockIdx.x * 256 + threadIdx.x) >> 6;
  const bool act = c < H;
  float wt[DA], wb[DA];
  float bias = 0.f;
  if (act) {
    bias = b_AP[c];
#pragma unroll
    for (int k = 0; k < DA; ++k) {
      wt[k] = W_AP[k * H + c];
      wb[k] = W_AP[(DA + k) * H + c];
    }
  }
  for (int a = wave; a < NA; a += nWaves) {
    const float* __restrict__ row = af + (size_t)a * DA;
    float xt = bias, xb = 0.f;
#pragma unroll
    for (int k = 0; k < DA; ++k) {
      const float f = row[k];
      xt = fmaf(f, wt[k], xt);
      xb = fmaf(f, wb[k], xb);
    }
    if (act) {
      Xt[(size_t)a * H + c] = xt;
      Xb[(size_t)a * H + c] = xb;
    }
  }
}

// ---------------------------------------------------------------------------
// K2a: streaming segmented sum: PAacc[atom] += relu(pf @ W_PA + b_PA).
// pair_split is sorted; each wave scans a contiguous pair chunk with a
// running accumulator, flushing one coalesced atomicAdd row per segment
// change (contention only at chunk boundaries). No binary search.
// ---------------------------------------------------------------------------
__global__ __launch_bounds__(256) void k_pa_scatter(
    const float* __restrict__ pf, const int* __restrict__ split,
    const float* __restrict__ W_PA, const float* __restrict__ b_PA,
    float* __restrict__ PAacc, int chunk) {
  const int c = threadIdx.x & 63;
  const int wave = (blockIdx.x * 256 + threadIdx.x) >> 6;
  const bool act = c < H;
  float wpa[DP];
  float bpa = 0.f;
  if (act) {
    bpa = b_PA[c];
#pragma unroll
    for (int k = 0; k < DP; ++k) wpa[k] = W_PA[k * H + c];
  }
  const int p0 = wave * chunk;
  const int pEnd = min(p0 + chunk, NP);
  int cur = -1;
  float acc = 0.f;
#pragma unroll 2
  for (int p = p0; p < pEnd; ++p) {
    const int sp = split[p];  // wave-uniform
    if (sp != cur) {          // uniform branch
      if (cur >= 0 && act) atomicAdd(&PAacc[(size_t)cur * H + c], acc);
      cur = sp;
      acc = 0.f;
    }
    const float2* __restrict__ pr = (const float2*)(pf + (size_t)p * DP);
    float v = bpa;
#pragma unroll
    for (int k = 0; k < 7; ++k) {
      const float2 f = pr[k];
      v = fmaf(f.x, wpa[2 * k], v);
      v = fmaf(f.y, wpa[2 * k + 1], v);
    }
    acc += fmaxf(v, 0.f);
  }
  if (cur >= 0 && act) atomicAdd(&PAacc[(size_t)cur * H + c], acc);
}

// ---------------------------------------------------------------------------
// K2b: atom branch, dense: AA = relu(af@W_AA+b); A = relu([AA|PA]@W_A+b_A).
// PA read directly from PAacc (coalesced row). No dependent-load chains.
// ---------------------------------------------------------------------------
__global__ __launch_bounds__(256) void k_atom_out(
    const float* __restrict__ af, const float* __restrict__ PAacc,
    const float* __restrict__ W_AA, const float* __restrict__ b_AA,
    const float* __restrict__ W_A, const float* __restrict__ b_A,
    float* __restrict__ A_out, int nWaves) {
  __shared__ float WA[2 * H][64];  // 25.6 KB, zero-padded cols
  __shared__ __align__(16) float buf[4][104];
  const int t = threadIdx.x;
  for (int idx = t; idx < 2 * H * 64; idx += 256) {
    const int k = idx >> 6, cc = idx & 63;
    WA[k][cc] = (cc < H) ? W_A[k * H + cc] : 0.f;
  }
  __syncthreads();
  const int w = t >> 6, c = t & 63;
  const bool act = c < H;
  float waa[DA];
  float baa = 0.f, ba = 0.f;
  if (act) {
    baa = b_AA[c];
    ba = b_A[c];
#pragma unroll
    for (int k = 0; k < DA; ++k) waa[k] = W_AA[k * H + c];
  }
  const int wave0 = blockIdx.x * 4 + w;
  for (int a = wave0; a < NA; a += nWaves) {
    const float* __restrict__ row = af + (size_t)a * DA;
    float aa = baa;
#pragma unroll
    for (int k = 0; k < DA; ++k) aa = fmaf(row[k], waa[k], aa);
    aa = fmaxf(aa, 0.f);
    const float pa = act ? PAacc[(size_t)a * H + c] : 0.f;
    if (act) { buf[w][c] = aa; buf[w][H + c] = pa; }
    __builtin_amdgcn_wave_barrier();
    float acc2 = ba;
    const float4* __restrict__ b4 = (const float4*)(&buf[w][0]);
#pragma unroll
    for (int k4 = 0; k4 < 25; ++k4) {
      const float4 vv = b4[k4];
      acc2 = fmaf(vv.x, WA[4 * k4 + 0][c], acc2);
      acc2 = fmaf(vv.y, WA[4 * k4 + 1][c], acc2);
      acc2 = fmaf(vv.z, WA[4 * k4 + 2][c], acc2);
      acc2 = fmaf(vv.w, WA[4 * k4 + 3][c], acc2);
    }
    __builtin_amdgcn_wave_barrier();
    if (act) A_out[(size_t)a * H + c] = fmaxf(acc2, 0.f);
  }
}

// ---------------------------------------------------------------------------
// K3: pair branch. Wave-independent 16-pair strips; phase 2 via bf16 MFMA.
//   A (LDS, bf16): [16 pairs][136] = S(0..49) | PP(50..99) | zeros(100..127)
//   B (global, bf16): WT[64 n][136 k] (W_P^T, padded), loaded EARLY (T14)
//   a2p indices prefetched to per-wave LDS (no per-q dependent scalar loads)
// ---------------------------------------------------------------------------
__global__ __launch_bounds__(256) void k_pair_out(
    const float* __restrict__ pf, const int* __restrict__ a2p,
    const float* __restrict__ Xt, const float* __restrict__ Xb,
    const float* __restrict__ W_PP, const float* __restrict__ b_PP,
    const short* __restrict__ WT, const float* __restrict__ b_P,
    float* __restrict__ P_out) {
  __shared__ __align__(16) short A[4][16 * ASTR];  // 4 x 4352 B
  __shared__ int IJ[4][32];
  const int t = threadIdx.x, w = t >> 6, l = t & 63;
  const int pBase = blockIdx.x * 64 + w * 16;
  short* __restrict__ As = &A[w][0];

  // prefetch this wave's 32 pair indices (coalesced, lanes 0..31)
  if (l < 32) IJ[w][l] = a2p[2 * pBase + l];
  // zero strip (covers K-pad cols 100..127)
  {
    const short8 z = {0, 0, 0, 0, 0, 0, 0, 0};
    for (int idx = l; idx < 16 * ASTR / 8; idx += 64)
      ((short8*)As)[idx] = z;
  }
  // early B-fragment loads (17 KB table, L1/L2-hot; used after phase 1)
  const int lr = l & 15, lg = l >> 4;
  short8 bfrag[16];
#pragma unroll
  for (int nt = 0; nt < 4; ++nt)
#pragma unroll
    for (int ks = 0; ks < 4; ++ks)
      bfrag[nt * 4 + ks] =
          *(const short8*)(WT + (nt * 16 + lr) * ASTR + ks * 32 + lg * 8);
  __builtin_amdgcn_wave_barrier();

  const bool act = l < H;
  float wpp[DP];
  float bpp = 0.f;
  if (act) {
    bpp = b_PP[l];
#pragma unroll
    for (int k = 0; k < DP; ++k) wpp[k] = W_PP[k * H + l];
  }
  // phase 1: 16 pairs, lane = feature column
#pragma unroll 4
  for (int q = 0; q < 16; ++q) {
    const int p = pBase + q;
    const int i = IJ[w][2 * q], j = IJ[w][2 * q + 1];
    if (act) {
      const float s = fmaxf(Xt[(size_t)i * H + l] + Xb[(size_t)j * H + l], 0.f) +
                      fmaxf(Xt[(size_t)j * H + l] + Xb[(size_t)i * H + l], 0.f);
      const float2* __restrict__ pr = (const float2*)(pf + (size_t)p * DP);
      float v = bpp;
#pragma unroll
      for (int k = 0; k < 7; ++k) {
        const float2 f = pr[k];
        v = fmaf(f.x, wpp[2 * k], v);
        v = fmaf(f.y, wpp[2 * k + 1], v);
      }
      As[q * ASTR + l] = f2bf(s);
      As[q * ASTR + H + l] = f2bf(fmaxf(v, 0.f));
    }
  }
  __builtin_amdgcn_wave_barrier();

  // phase 2: 16x64 output strip = 4 col-tiles x 4 K-steps of MFMA
  f32x4 acc[4];
#pragma unroll
  for (int nt = 0; nt < 4; ++nt) {
    const int col = nt * 16 + lr;
    const float b = (col < H) ? b_P[col] : 0.f;
    acc[nt] = (f32x4){b, b, b, b};
  }
  short8 afr[4];
#pragma unroll
  for (int ks = 0; ks < 4; ++ks)
    afr[ks] = *(const short8*)(As + lr * ASTR + ks * 32 + lg * 8);
#pragma unroll
  for (int nt = 0; nt < 4; ++nt)
#pragma unroll
    for (int ks = 0; ks < 4; ++ks)
      acc[nt] = __builtin_amdgcn_mfma_f32_16x16x32_bf16(afr[ks], bfrag[nt * 4 + ks],
                                                        acc[nt], 0, 0, 0);
  // epilogue: relu + store (cols >= 50 masked)
#pragma unroll
  for (int nt = 0; nt < 4; ++nt) {
    const int col = nt * 16 + lr;
    if (col < H) {
#pragma unroll
      for (int r = 0; r < 4; ++r) {
        const size_t p = (size_t)(pBase + lg * 4 + r);
        P_out[p * H + col] = fmaxf(acc[nt][r], 0.f);
      }
    }
  }
}

extern "C" void kernel_launch(void* const* d_in, const int* in_sizes, int n_in,
                              void* d_out, int out_size, void* d_ws, size_t ws_size,
                              hipStream_t stream) {
  const float* af   = (const float*)d_in[0];
  const float* pf   = (const float*)d_in[1];
  const int*   split= (const int*)d_in[2];
  const int*   a2p  = (const int*)d_in[3];
  const float* W_AA = (const float*)d_in[4];
  const float* b_AA = (const float*)d_in[5];
  const float* W_PA = (const float*)d_in[6];
  const float* b_PA = (const float*)d_in[7];
  const float* W_A  = (const float*)d_in[8];
  const float* b_A  = (const float*)d_in[9];
  const float* W_AP = (const float*)d_in[10];
  const float* b_AP = (const float*)d_in[11];
  const float* W_PP = (const float*)d_in[12];
  const float* b_PP = (const float*)d_in[13];
  const float* W_P  = (const float*)d_in[14];
  const float* b_P  = (const float*)d_in[15];

  float* A_out = (float*)d_out;
  float* P_out = A_out + (size_t)NA * H;
  float* Xt = (float*)d_ws;                         // NA*H f32
  float* Xb = Xt + (size_t)NA * H;                  // NA*H f32
  float* PAacc = Xb + (size_t)NA * H;               // NA*H f32
  short* WT = (short*)(PAacc + (size_t)NA * H);     // 64*136 bf16

  const int nWaves = 2048 * 4;
  const int chunk = (NP + nWaves - 1) / nWaves;  // 196

  k_zero<<<2048, 256, 0, stream>>>((float4*)PAacc, NA * H / 4);
  k_prep_wt<<<(64 * ASTR + 255) / 256, 256, 0, stream>>>(W_P, WT);
  k_atom_ap<<<2048, 256, 0, stream>>>(af, W_AP, b_AP, Xt, Xb, nWaves);
  k_pa_scatter<<<2048, 256, 0, stream>>>(pf, split, W_PA, b_PA, PAacc, chunk);
  k_atom_out<<<2048, 256, 0, stream>>>(af, PAacc, W_AA, b_AA, W_A, b_A, A_out,
                                       nWaves);
  k_pair_out<<<NP / 64, 256, 0, stream>>>(pf, a2p, Xt, Xb, W_PP, b_PP, WT, b_P,
                                          P_out);
}

// Round 6
// 1085.131 us; speedup vs baseline: 12.7416x; 1.4916x over previous
//
#include <hip/hip_runtime.h>
#include <hip/hip_bf16.h>

#define NA 100000
#define NP 1600000
#define DA 75
#define DP 14
#define H  50
#define ASTR 136  // bf16 elems per LDS A row / WT row: 128 (padded K) + 8 pad

typedef short short8 __attribute__((ext_vector_type(8)));
typedef float f32x4 __attribute__((ext_vector_type(4)));

static __device__ __forceinline__ short f2bf(float x) {
  __hip_bfloat16 b = __float2bfloat16(x);
  return *reinterpret_cast<short*>(&b);
}
static __device__ __forceinline__ unsigned short f2bfu(float x) {
  __hip_bfloat16 b = __float2bfloat16(x);
  return *reinterpret_cast<unsigned short*>(&b);
}
static __device__ __forceinline__ float bits2f(unsigned int u) {
  return __builtin_bit_cast(float, u);
}

// ---------------------------------------------------------------------------
// K-1: zero PAacc (d_ws is poisoned 0xAA before every launch).
// ---------------------------------------------------------------------------
__global__ __launch_bounds__(256) void k_zero(float4* __restrict__ p, int n4) {
  const int stride = gridDim.x * 256;
  for (int i = blockIdx.x * 256 + threadIdx.x; i < n4; i += stride)
    p[i] = make_float4(0.f, 0.f, 0.f, 0.f);
}

// ---------------------------------------------------------------------------
// K0: WT[n][k] = bf16(W_P[k][n]), zero-padded to [64][136] (K pad 100->128).
// ---------------------------------------------------------------------------
__global__ __launch_bounds__(256) void k_prep_wt(const float* __restrict__ W_P,
                                                 short* __restrict__ WT) {
  const int idx = blockIdx.x * 256 + threadIdx.x;
  if (idx < 64 * ASTR) {
    const int n = idx / ASTR, k = idx % ASTR;
    const float v = (n < H && k < 2 * H) ? W_P[k * H + n] : 0.f;
    WT[idx] = f2bf(v);
  }
}

// ---------------------------------------------------------------------------
// K1: XtXb[a][c] = pack(bf16(Xb), bf16(Xt))  (hi = Xb, lo = Xt)
//   Xt = af @ W_AP[:75] + b_AP ; Xb = af @ W_AP[75:]
// ---------------------------------------------------------------------------
__global__ __launch_bounds__(256) void k_atom_ap(
    const float* __restrict__ af, const float* __restrict__ W_AP,
    const float* __restrict__ b_AP, unsigned int* __restrict__ XtXb,
    int nWaves) {
  const int c = threadIdx.x & 63;
  const int wave = (blockIdx.x * 256 + threadIdx.x) >> 6;
  const bool act = c < H;
  float wt[DA], wb[DA];
  float bias = 0.f;
  if (act) {
    bias = b_AP[c];
#pragma unroll
    for (int k = 0; k < DA; ++k) {
      wt[k] = W_AP[k * H + c];
      wb[k] = W_AP[(DA + k) * H + c];
    }
  }
  for (int a = wave; a < NA; a += nWaves) {
    const float* __restrict__ row = af + (size_t)a * DA;
    float xt = bias, xb = 0.f;
#pragma unroll
    for (int k = 0; k < DA; ++k) {
      const float f = row[k];
      xt = fmaf(f, wt[k], xt);
      xb = fmaf(f, wb[k], xb);
    }
    if (act) {
      const unsigned int u =
          ((unsigned int)f2bfu(xb) << 16) | (unsigned int)f2bfu(xt);
      XtXb[(size_t)a * H + c] = u;
    }
  }
}

// ---------------------------------------------------------------------------
// K3: pair branch + fused PA segment-scatter. Wave-independent 16-pair strips.
//   gather: 2 packed rows per pair (atom i, atom j), each uint = (xb|xt)
//   S = relu(xt_i+xb_j)+relu(xt_j+xb_i); PP = relu(pf@W_PP+b)
//   PA = relu(pf@W_PA+b) accumulated per split-segment, atomicAdd flush
//   phase 2: P[16x64] strip via 16x16x32 bf16 MFMA, B lazy-loaded from WT
// ---------------------------------------------------------------------------
__global__ __launch_bounds__(256) void k_pair_out(
    const float* __restrict__ pf, const int* __restrict__ a2p,
    const int* __restrict__ split, const unsigned int* __restrict__ XtXb,
    const float* __restrict__ W_PP, const float* __restrict__ b_PP,
    const float* __restrict__ W_PA, const float* __restrict__ b_PA,
    const short* __restrict__ WT, const float* __restrict__ b_P,
    float* __restrict__ P_out, float* __restrict__ PAacc) {
  __shared__ __align__(16) short A[4][16 * ASTR];  // 4 x 4352 B
  __shared__ int IJ[4][32];
  __shared__ int SPL[4][16];
  const int t = threadIdx.x, w = t >> 6, l = t & 63;
  const int pBase = blockIdx.x * 64 + w * 16;
  short* __restrict__ As = &A[w][0];

  // prefetch indices (coalesced) + zero strip (covers K-pad cols 100..127)
  if (l < 32) IJ[w][l] = a2p[2 * pBase + l];
  else if (l < 48) SPL[w][l - 32] = split[pBase + (l - 32)];
  {
    const short8 z = {0, 0, 0, 0, 0, 0, 0, 0};
    for (int idx = l; idx < 16 * ASTR / 8; idx += 64)
      ((short8*)As)[idx] = z;
  }
  __builtin_amdgcn_wave_barrier();

  const bool act = l < H;
  float wpp[DP], wpa[DP];
  float bpp = 0.f, bpa = 0.f;
  if (act) {
    bpp = b_PP[l];
    bpa = b_PA[l];
#pragma unroll
    for (int k = 0; k < DP; ++k) {
      wpp[k] = W_PP[k * H + l];
      wpa[k] = W_PA[k * H + l];
    }
  }
  // phase 1: 16 pairs, lane = feature column
  int cur = -1;
  float accpa = 0.f;
#pragma unroll 4
  for (int q = 0; q < 16; ++q) {
    const int p = pBase + q;
    const int i = IJ[w][2 * q], j = IJ[w][2 * q + 1];
    const int sp = SPL[w][q];  // wave-uniform
    if (sp != cur) {
      if (cur >= 0 && act) atomicAdd(&PAacc[(size_t)cur * H + l], accpa);
      cur = sp;
      accpa = 0.f;
    }
    if (act) {
      const unsigned int ui = XtXb[(size_t)i * H + l];
      const unsigned int uj = XtXb[(size_t)j * H + l];
      const float xt_i = bits2f(ui << 16), xb_i = bits2f(ui & 0xffff0000u);
      const float xt_j = bits2f(uj << 16), xb_j = bits2f(uj & 0xffff0000u);
      const float s = fmaxf(xt_i + xb_j, 0.f) + fmaxf(xt_j + xb_i, 0.f);
      const float2* __restrict__ pr = (const float2*)(pf + (size_t)p * DP);
      float vpp = bpp, vpa = bpa;
#pragma unroll
      for (int k = 0; k < 7; ++k) {
        const float2 f = pr[k];
        vpp = fmaf(f.x, wpp[2 * k], vpp);
        vpp = fmaf(f.y, wpp[2 * k + 1], vpp);
        vpa = fmaf(f.x, wpa[2 * k], vpa);
        vpa = fmaf(f.y, wpa[2 * k + 1], vpa);
      }
      accpa += fmaxf(vpa, 0.f);
      As[q * ASTR + l] = f2bf(s);
      As[q * ASTR + H + l] = f2bf(fmaxf(vpp, 0.f));
    }
  }
  if (cur >= 0 && act) atomicAdd(&PAacc[(size_t)cur * H + l], accpa);
  __builtin_amdgcn_wave_barrier();

  // phase 2: 16x64 output strip = 4 col-tiles x 4 K-steps of MFMA
  const int lr = l & 15, lg = l >> 4;
  short8 afr[4];
#pragma unroll
  for (int ks = 0; ks < 4; ++ks)
    afr[ks] = *(const short8*)(As + lr * ASTR + ks * 32 + lg * 8);
#pragma unroll
  for (int nt = 0; nt < 4; ++nt) {
    const int col = nt * 16 + lr;
    const float b = (col < H) ? b_P[col] : 0.f;
    f32x4 acc = (f32x4){b, b, b, b};
    short8 bf[4];
#pragma unroll
    for (int ks = 0; ks < 4; ++ks)
      bf[ks] = *(const short8*)(WT + (size_t)col * ASTR + ks * 32 + lg * 8);
#pragma unroll
    for (int ks = 0; ks < 4; ++ks)
      acc = __builtin_amdgcn_mfma_f32_16x16x32_bf16(afr[ks], bf[ks], acc, 0, 0, 0);
    if (col < H) {
#pragma unroll
      for (int r = 0; r < 4; ++r) {
        const size_t p = (size_t)(pBase + lg * 4 + r);
        P_out[p * H + col] = fmaxf(acc[r], 0.f);
      }
    }
  }
}

// ---------------------------------------------------------------------------
// K2b: atom branch, dense: AA = relu(af@W_AA+b); A = relu([AA|PA]@W_A+b_A).
// Runs AFTER k_pair_out (PAacc complete). No dependent-load chains.
// ---------------------------------------------------------------------------
__global__ __launch_bounds__(256) void k_atom_out(
    const float* __restrict__ af, const float* __restrict__ PAacc,
    const float* __restrict__ W_AA, const float* __restrict__ b_AA,
    const float* __restrict__ W_A, const float* __restrict__ b_A,
    float* __restrict__ A_out, int nWaves) {
  __shared__ float WA[2 * H][64];  // 25.6 KB, zero-padded cols
  __shared__ __align__(16) float buf[4][104];
  const int t = threadIdx.x;
  for (int idx = t; idx < 2 * H * 64; idx += 256) {
    const int k = idx >> 6, cc = idx & 63;
    WA[k][cc] = (cc < H) ? W_A[k * H + cc] : 0.f;
  }
  __syncthreads();
  const int w = t >> 6, c = t & 63;
  const bool act = c < H;
  float waa[DA];
  float baa = 0.f, ba = 0.f;
  if (act) {
    baa = b_AA[c];
    ba = b_A[c];
#pragma unroll
    for (int k = 0; k < DA; ++k) waa[k] = W_AA[k * H + c];
  }
  const int wave0 = blockIdx.x * 4 + w;
  for (int a = wave0; a < NA; a += nWaves) {
    const float* __restrict__ row = af + (size_t)a * DA;
    float aa = baa;
#pragma unroll
    for (int k = 0; k < DA; ++k) aa = fmaf(row[k], waa[k], aa);
    aa = fmaxf(aa, 0.f);
    const float pa = act ? PAacc[(size_t)a * H + c] : 0.f;
    if (act) { buf[w][c] = aa; buf[w][H + c] = pa; }
    __builtin_amdgcn_wave_barrier();
    float acc2 = ba;
    const float4* __restrict__ b4 = (const float4*)(&buf[w][0]);
#pragma unroll
    for (int k4 = 0; k4 < 25; ++k4) {
      const float4 vv = b4[k4];
      acc2 = fmaf(vv.x, WA[4 * k4 + 0][c], acc2);
      acc2 = fmaf(vv.y, WA[4 * k4 + 1][c], acc2);
      acc2 = fmaf(vv.z, WA[4 * k4 + 2][c], acc2);
      acc2 = fmaf(vv.w, WA[4 * k4 + 3][c], acc2);
    }
    __builtin_amdgcn_wave_barrier();
    if (act) A_out[(size_t)a * H + c] = fmaxf(acc2, 0.f);
  }
}

extern "C" void kernel_launch(void* const* d_in, const int* in_sizes, int n_in,
                              void* d_out, int out_size, void* d_ws, size_t ws_size,
                              hipStream_t stream) {
  const float* af   = (const float*)d_in[0];
  const float* pf   = (const float*)d_in[1];
  const int*   split= (const int*)d_in[2];
  const int*   a2p  = (const int*)d_in[3];
  const float* W_AA = (const float*)d_in[4];
  const float* b_AA = (const float*)d_in[5];
  const float* W_PA = (const float*)d_in[6];
  const float* b_PA = (const float*)d_in[7];
  const float* W_A  = (const float*)d_in[8];
  const float* b_A  = (const float*)d_in[9];
  const float* W_AP = (const float*)d_in[10];
  const float* b_AP = (const float*)d_in[11];
  const float* W_PP = (const float*)d_in[12];
  const float* b_PP = (const float*)d_in[13];
  const float* W_P  = (const float*)d_in[14];
  const float* b_P  = (const float*)d_in[15];

  float* A_out = (float*)d_out;
  float* P_out = A_out + (size_t)NA * H;
  unsigned int* XtXb = (unsigned int*)d_ws;         // NA*H uint (packed bf16)
  float* PAacc = (float*)(XtXb + (size_t)NA * H);   // NA*H f32
  short* WT = (short*)(PAacc + (size_t)NA * H);     // 64*136 bf16

  const int nWaves = 2048 * 4;

  k_zero<<<2048, 256, 0, stream>>>((float4*)PAacc, NA * H / 4);
  k_prep_wt<<<(64 * ASTR + 255) / 256, 256, 0, stream>>>(W_P, WT);
  k_atom_ap<<<2048, 256, 0, stream>>>(af, W_AP, b_AP, XtXb, nWaves);
  k_pair_out<<<NP / 64, 256, 0, stream>>>(pf, a2p, split, XtXb, W_PP, b_PP,
                                          W_PA, b_PA, WT, b_P, P_out, PAacc);
  k_atom_out<<<2048, 256, 0, stream>>>(af, PAacc, W_AA, b_AA, W_A, b_A, A_out,
                                       nWaves);
}

// Round 7
// 842.498 us; speedup vs baseline: 16.4111x; 1.2880x over previous
//
#include <hip/hip_runtime.h>
#include <hip/hip_bf16.h>

#define NA 100000
#define NP 1600000
#define DA 75
#define DP 14
#define H  50
#define ASTR 136  // bf16 pitch for K=128-padded rows (WT, WTP, pair A-tile)
#define KAP 104   // bf16 pitch for K=96-padded rows (Atile, WTA)

typedef short short8 __attribute__((ext_vector_type(8)));
typedef float f32x4 __attribute__((ext_vector_type(4)));

static __device__ __forceinline__ short f2bf(float x) {
  __hip_bfloat16 b = __float2bfloat16(x);
  return *reinterpret_cast<short*>(&b);
}
static __device__ __forceinline__ unsigned short f2bfu(float x) {
  __hip_bfloat16 b = __float2bfloat16(x);
  return *reinterpret_cast<unsigned short*>(&b);
}
static __device__ __forceinline__ float bits2f(unsigned int u) {
  return __builtin_bit_cast(float, u);
}

// ---------------------------------------------------------------------------
// K-1: zero PAacc (d_ws is poisoned 0xAA before every launch).
// ---------------------------------------------------------------------------
__global__ __launch_bounds__(256) void k_zero(float4* __restrict__ p, int n4) {
  const int stride = gridDim.x * 256;
  for (int i = blockIdx.x * 256 + threadIdx.x; i < n4; i += stride)
    p[i] = make_float4(0.f, 0.f, 0.f, 0.f);
}

// ---------------------------------------------------------------------------
// K0: build all transposed/padded bf16 weight tables in one kernel.
//   WT [64][136]:  WT[n][k]  = W_P[k][n]   (n<50, k<100)          pair GEMM
//   WTA[160][104]: WTA[n][k] = n<50: W_AP[k][n] | n<100: W_AP[75+k][n-50]
//                              | n<150: W_AA[k][n-100]   (k<75)   atom-pre GEMM
//   WTP[64][136]:  WTP[n][k] = W_A[k][n]   (n<50, k<100)          atom-out GEMM
// ---------------------------------------------------------------------------
#define WT_ELEMS  (64 * ASTR)
#define WTA_ELEMS (160 * KAP)
#define WTP_ELEMS (64 * ASTR)
__global__ __launch_bounds__(256) void k_prep_all(
    const float* __restrict__ W_P, const float* __restrict__ W_AP,
    const float* __restrict__ W_AA, const float* __restrict__ W_A,
    short* __restrict__ WT, short* __restrict__ WTA, short* __restrict__ WTP) {
  int idx = blockIdx.x * 256 + threadIdx.x;
  if (idx < WT_ELEMS) {
    const int n = idx / ASTR, k = idx % ASTR;
    WT[idx] = f2bf((n < H && k < 2 * H) ? W_P[k * H + n] : 0.f);
    return;
  }
  idx -= WT_ELEMS;
  if (idx < WTA_ELEMS) {
    const int n = idx / KAP, k = idx % KAP;
    float v = 0.f;
    if (k < DA) {
      if (n < H) v = W_AP[k * H + n];
      else if (n < 2 * H) v = W_AP[(DA + k) * H + (n - H)];
      else if (n < 3 * H) v = W_AA[k * H + (n - 2 * H)];
    }
    WTA[idx] = f2bf(v);
    return;
  }
  idx -= WTA_ELEMS;
  if (idx < WTP_ELEMS) {
    const int n = idx / ASTR, k = idx % ASTR;
    WTP[idx] = f2bf((n < H && k < 2 * H) ? W_A[k * H + n] : 0.f);
  }
}

// ---------------------------------------------------------------------------
// K1: atom-pre GEMM via MFMA: [64 atoms x 75] @ WTA^T -> Xt|Xb|AA (150 cols).
// Coalesced af staging -> bf16 LDS tile; 10 n-tiles x 3 K-steps per wave;
// epilogue adds biases, bounces through LDS, coalesced packed stores.
// ---------------------------------------------------------------------------
__global__ __launch_bounds__(256) void k_atom_pre(
    const float* __restrict__ af, const short* __restrict__ WTA,
    const float* __restrict__ b_AP, const float* __restrict__ b_AA,
    unsigned int* __restrict__ XtXb, unsigned short* __restrict__ AAg) {
  __shared__ __align__(16) short Atile[64 * KAP];      // 13.3 KB
  __shared__ unsigned short XTl[64 * H];               // 6.4 KB
  __shared__ unsigned short XBl[64 * H];               // 6.4 KB
  __shared__ unsigned short AAl[64 * H];               // 6.4 KB
  const int t = threadIdx.x, w = t >> 6, l = t & 63;
  const int a0 = blockIdx.x * 64;
  // zero A tile (covers K-pad 75..95 and pitch pad)
  {
    const short8 z = {0, 0, 0, 0, 0, 0, 0, 0};
    for (int i = t; i < 64 * KAP / 8; i += 256) ((short8*)Atile)[i] = z;
  }
  __syncthreads();
  // stage af rows (fully coalesced: contiguous range a0*75 .. a0*75+4799)
  for (int i = t; i < 64 * DA; i += 256) {
    const int ra = i / DA, k = i - ra * DA;
    const int a = a0 + ra;
    if (a < NA) Atile[ra * KAP + k] = f2bf(af[(size_t)a0 * DA + i]);
  }
  __syncthreads();
  // MFMA: wave w owns atoms a0 + w*16 .. +15
  const int lr = l & 15, lg = l >> 4;
  short8 afr[3];
#pragma unroll
  for (int ks = 0; ks < 3; ++ks)
    afr[ks] = *(const short8*)(Atile + (w * 16 + lr) * KAP + ks * 32 + lg * 8);
#pragma unroll
  for (int nt = 0; nt < 10; ++nt) {
    const int n = nt * 16 + lr;
    short8 bf[3];
#pragma unroll
    for (int ks = 0; ks < 3; ++ks)
      bf[ks] = *(const short8*)(WTA + (size_t)n * KAP + ks * 32 + lg * 8);
    f32x4 acc = (f32x4){0.f, 0.f, 0.f, 0.f};
#pragma unroll
    for (int ks = 0; ks < 3; ++ks)
      acc = __builtin_amdgcn_mfma_f32_16x16x32_bf16(afr[ks], bf[ks], acc, 0, 0, 0);
#pragma unroll
    for (int r = 0; r < 4; ++r) {
      const int arow = w * 16 + lg * 4 + r;
      const float v = acc[r];
      if (n < H) XTl[arow * H + n] = f2bfu(v + b_AP[n]);
      else if (n < 2 * H) XBl[arow * H + (n - H)] = f2bfu(v);
      else if (n < 3 * H) AAl[arow * H + (n - 2 * H)] = f2bfu(fmaxf(v + b_AA[n - 2 * H], 0.f));
    }
  }
  __syncthreads();
  // coalesced packed stores
  for (int i = t; i < 64 * H; i += 256) {
    const int a = a0 + i / H;
    if (a < NA) {
      XtXb[(size_t)a0 * H + i] =
          ((unsigned int)XBl[i] << 16) | (unsigned int)XTl[i];
      AAg[(size_t)a0 * H + i] = AAl[i];
    }
  }
}

// ---------------------------------------------------------------------------
// K3: pair branch + fused PA segment-scatter (UNCHANGED from round 6).
// ---------------------------------------------------------------------------
__global__ __launch_bounds__(256) void k_pair_out(
    const float* __restrict__ pf, const int* __restrict__ a2p,
    const int* __restrict__ split, const unsigned int* __restrict__ XtXb,
    const float* __restrict__ W_PP, const float* __restrict__ b_PP,
    const float* __restrict__ W_PA, const float* __restrict__ b_PA,
    const short* __restrict__ WT, const float* __restrict__ b_P,
    float* __restrict__ P_out, float* __restrict__ PAacc) {
  __shared__ __align__(16) short A[4][16 * ASTR];  // 4 x 4352 B
  __shared__ int IJ[4][32];
  __shared__ int SPL[4][16];
  const int t = threadIdx.x, w = t >> 6, l = t & 63;
  const int pBase = blockIdx.x * 64 + w * 16;
  short* __restrict__ As = &A[w][0];

  if (l < 32) IJ[w][l] = a2p[2 * pBase + l];
  else if (l < 48) SPL[w][l - 32] = split[pBase + (l - 32)];
  {
    const short8 z = {0, 0, 0, 0, 0, 0, 0, 0};
    for (int idx = l; idx < 16 * ASTR / 8; idx += 64)
      ((short8*)As)[idx] = z;
  }
  __builtin_amdgcn_wave_barrier();

  const bool act = l < H;
  float wpp[DP], wpa[DP];
  float bpp = 0.f, bpa = 0.f;
  if (act) {
    bpp = b_PP[l];
    bpa = b_PA[l];
#pragma unroll
    for (int k = 0; k < DP; ++k) {
      wpp[k] = W_PP[k * H + l];
      wpa[k] = W_PA[k * H + l];
    }
  }
  int cur = -1;
  float accpa = 0.f;
#pragma unroll 4
  for (int q = 0; q < 16; ++q) {
    const int p = pBase + q;
    const int i = IJ[w][2 * q], j = IJ[w][2 * q + 1];
    const int sp = SPL[w][q];  // wave-uniform
    if (sp != cur) {
      if (cur >= 0 && act) atomicAdd(&PAacc[(size_t)cur * H + l], accpa);
      cur = sp;
      accpa = 0.f;
    }
    if (act) {
      const unsigned int ui = XtXb[(size_t)i * H + l];
      const unsigned int uj = XtXb[(size_t)j * H + l];
      const float xt_i = bits2f(ui << 16), xb_i = bits2f(ui & 0xffff0000u);
      const float xt_j = bits2f(uj << 16), xb_j = bits2f(uj & 0xffff0000u);
      const float s = fmaxf(xt_i + xb_j, 0.f) + fmaxf(xt_j + xb_i, 0.f);
      const float2* __restrict__ pr = (const float2*)(pf + (size_t)p * DP);
      float vpp = bpp, vpa = bpa;
#pragma unroll
      for (int k = 0; k < 7; ++k) {
        const float2 f = pr[k];
        vpp = fmaf(f.x, wpp[2 * k], vpp);
        vpp = fmaf(f.y, wpp[2 * k + 1], vpp);
        vpa = fmaf(f.x, wpa[2 * k], vpa);
        vpa = fmaf(f.y, wpa[2 * k + 1], vpa);
      }
      accpa += fmaxf(vpa, 0.f);
      As[q * ASTR + l] = f2bf(s);
      As[q * ASTR + H + l] = f2bf(fmaxf(vpp, 0.f));
    }
  }
  if (cur >= 0 && act) atomicAdd(&PAacc[(size_t)cur * H + l], accpa);
  __builtin_amdgcn_wave_barrier();

  const int lr = l & 15, lg = l >> 4;
  short8 afr[4];
#pragma unroll
  for (int ks = 0; ks < 4; ++ks)
    afr[ks] = *(const short8*)(As + lr * ASTR + ks * 32 + lg * 8);
#pragma unroll
  for (int nt = 0; nt < 4; ++nt) {
    const int col = nt * 16 + lr;
    const float b = (col < H) ? b_P[col] : 0.f;
    f32x4 acc = (f32x4){b, b, b, b};
    short8 bf[4];
#pragma unroll
    for (int ks = 0; ks < 4; ++ks)
      bf[ks] = *(const short8*)(WT + (size_t)col * ASTR + ks * 32 + lg * 8);
#pragma unroll
    for (int ks = 0; ks < 4; ++ks)
      acc = __builtin_amdgcn_mfma_f32_16x16x32_bf16(afr[ks], bf[ks], acc, 0, 0, 0);
    if (col < H) {
#pragma unroll
      for (int r = 0; r < 4; ++r) {
        const size_t p = (size_t)(pBase + lg * 4 + r);
        P_out[p * H + col] = fmaxf(acc[r], 0.f);
      }
    }
  }
}

// ---------------------------------------------------------------------------
// K2: atom output via MFMA: A = relu([AA|PA] @ W_A + b_A).
// Per-wave 16-atom strip; coalesced AAg/PAacc reads -> bf16 S tile; 16 MFMAs.
// ---------------------------------------------------------------------------
__global__ __launch_bounds__(256) void k_atom_out(
    const unsigned short* __restrict__ AAg, const float* __restrict__ PAacc,
    const short* __restrict__ WTP, const float* __restrict__ b_A,
    float* __restrict__ A_out) {
  __shared__ __align__(16) short S[4][16 * ASTR];
  const int t = threadIdx.x, w = t >> 6, l = t & 63;
  const int strip = blockIdx.x * 64 + w * 16;
  short* __restrict__ Ss = &S[w][0];
  {
    const short8 z = {0, 0, 0, 0, 0, 0, 0, 0};
    for (int i = l; i < 16 * ASTR / 8; i += 64) ((short8*)Ss)[i] = z;
  }
  __builtin_amdgcn_wave_barrier();
  const bool act = l < H;
#pragma unroll 4
  for (int q = 0; q < 16; ++q) {
    const int a = strip + q;
    if (act && a < NA) {
      Ss[q * ASTR + l] = (short)AAg[(size_t)a * H + l];
      Ss[q * ASTR + H + l] = f2bf(PAacc[(size_t)a * H + l]);
    }
  }
  __builtin_amdgcn_wave_barrier();
  const int lr = l & 15, lg = l >> 4;
  short8 afr[4];
#pragma unroll
  for (int ks = 0; ks < 4; ++ks)
    afr[ks] = *(const short8*)(Ss + lr * ASTR + ks * 32 + lg * 8);
#pragma unroll
  for (int nt = 0; nt < 4; ++nt) {
    const int col = nt * 16 + lr;
    const float b = (col < H) ? b_A[col] : 0.f;
    f32x4 acc = (f32x4){b, b, b, b};
    short8 bf[4];
#pragma unroll
    for (int ks = 0; ks < 4; ++ks)
      bf[ks] = *(const short8*)(WTP + (size_t)col * ASTR + ks * 32 + lg * 8);
#pragma unroll
    for (int ks = 0; ks < 4; ++ks)
      acc = __builtin_amdgcn_mfma_f32_16x16x32_bf16(afr[ks], bf[ks], acc, 0, 0, 0);
    if (col < H) {
#pragma unroll
      for (int r = 0; r < 4; ++r) {
        const int a = strip + lg * 4 + r;
        if (a < NA) A_out[(size_t)a * H + col] = fmaxf(acc[r], 0.f);
      }
    }
  }
}

extern "C" void kernel_launch(void* const* d_in, const int* in_sizes, int n_in,
                              void* d_out, int out_size, void* d_ws, size_t ws_size,
                              hipStream_t stream) {
  const float* af   = (const float*)d_in[0];
  const float* pf   = (const float*)d_in[1];
  const int*   split= (const int*)d_in[2];
  const int*   a2p  = (const int*)d_in[3];
  const float* W_AA = (const float*)d_in[4];
  const float* b_AA = (const float*)d_in[5];
  const float* W_PA = (const float*)d_in[6];
  const float* b_PA = (const float*)d_in[7];
  const float* W_A  = (const float*)d_in[8];
  const float* b_A  = (const float*)d_in[9];
  const float* W_AP = (const float*)d_in[10];
  const float* b_AP = (const float*)d_in[11];
  const float* W_PP = (const float*)d_in[12];
  const float* b_PP = (const float*)d_in[13];
  const float* W_P  = (const float*)d_in[14];
  const float* b_P  = (const float*)d_in[15];

  float* A_out = (float*)d_out;
  float* P_out = A_out + (size_t)NA * H;
  unsigned int* XtXb = (unsigned int*)d_ws;            // NA*H uint (bf16 xb|xt)
  float* PAacc = (float*)(XtXb + (size_t)NA * H);      // NA*H f32
  unsigned short* AAg = (unsigned short*)(PAacc + (size_t)NA * H);  // NA*H bf16
  short* WT  = (short*)(AAg + (size_t)NA * H);         // 64*136
  short* WTA = WT + WT_ELEMS;                          // 160*104
  short* WTP = WTA + WTA_ELEMS;                        // 64*136

  const int nAtomBlocks = (NA + 63) / 64;  // 1563
  const int nPrep = (WT_ELEMS + WTA_ELEMS + WTP_ELEMS + 255) / 256;

  k_zero<<<2048, 256, 0, stream>>>((float4*)PAacc, NA * H / 4);
  k_prep_all<<<nPrep, 256, 0, stream>>>(W_P, W_AP, W_AA, W_A, WT, WTA, WTP);
  k_atom_pre<<<nAtomBlocks, 256, 0, stream>>>(af, WTA, b_AP, b_AA, XtXb, AAg);
  k_pair_out<<<NP / 64, 256, 0, stream>>>(pf, a2p, split, XtXb, W_PP, b_PP,
                                          W_PA, b_PA, WT, b_P, P_out, PAacc);
  k_atom_out<<<nAtomBlocks, 256, 0, stream>>>(AAg, PAacc, WTP, b_A, A_out);
}